// Round 21
// baseline (106.995 us; speedup 1.0000x reference)
//
#include <hip/hip_runtime.h>
#include <math.h>

#define BATCH 2
#define SEQ   2048
#define DMODEL 1024
#define NHEAD 16
#define HEADD 64
#define MROWS 4096

typedef __attribute__((ext_vector_type(8))) __bf16 bf16x8;
typedef __attribute__((ext_vector_type(4))) float f32x4;

__device__ __forceinline__ ushort f2bf(float f) {
    uint u = __float_as_uint(f);
    u += 0x7fffu + ((u >> 16) & 1u);
    return (ushort)(u >> 16);
}
__device__ __forceinline__ float bf2f(ushort h) {
    return __uint_as_float(((uint)h) << 16);
}
__device__ __forceinline__ ushort4 pack4bf(float a, float b, float c, float d) {
    union { __bf16 h[4]; ushort4 u; } p;
    p.h[0] = (__bf16)a; p.h[1] = (__bf16)b; p.h[2] = (__bf16)c; p.h[3] = (__bf16)d;
    return p.u;
}

#define GLD16(gsrc, ldst)                                                         \
    __builtin_amdgcn_global_load_lds(                                             \
        (const __attribute__((address_space(1))) unsigned int*)(gsrc),            \
        (__attribute__((address_space(3))) unsigned int*)(ldst), 16, 0, 0)

// Q pre-scale: (1/sqrt(64)) * log2(e)  -> softmax in exp2 domain
#define QSCALE 0.1803368801111204f
#define MFIX   16.0f   // fixed softmax "max", folded into QK MFMA C-init

// ---------------- merged prep: z<3 -> W^T->wtc; z==3 -> Wo^T->woh; z==4 -> x split ----------------
__global__ __launch_bounds__(256) void prep(const float* __restrict__ x,
                                            const float* __restrict__ Wq,
                                            const float* __restrict__ Wk,
                                            const float* __restrict__ Wv,
                                            const float* __restrict__ Wo,
                                            ushort* __restrict__ wtc,
                                            ushort* __restrict__ woh,
                                            ushort* __restrict__ xh) {
    const int z = blockIdx.z;
    const int t = threadIdx.x;
    if (z == 4) {
        const int n4 = MROWS * DMODEL / 4;
        int i = (blockIdx.y * 16 + blockIdx.x) * 256 + t;
        const int stride = 256 * 256;
        for (; i < n4; i += stride) {
            const float4 v = reinterpret_cast<const float4*>(x)[i];
            ushort4 h;
            h.x = f2bf(v.x); h.y = f2bf(v.y); h.z = f2bf(v.z); h.w = f2bf(v.w);
            reinterpret_cast<ushort4*>(xh)[i] = h;
        }
        return;
    }
    const float* W = (z == 0) ? Wq : (z == 1) ? Wk : (z == 2) ? Wv : Wo;
    __shared__ float T[64][68];
    const int k0 = blockIdx.y * 64, n0 = blockIdx.x * 64;
    {
        const int r = t >> 2, c0 = (t & 3) * 16;
        #pragma unroll
        for (int j = 0; j < 4; ++j)
            *reinterpret_cast<float4*>(&T[r][c0 + j * 4]) =
                *reinterpret_cast<const float4*>(&W[(size_t)(k0 + r) * DMODEL + n0 + c0 + j * 4]);
    }
    __syncthreads();
    const int nl = t >> 2, kq = t & 3;
    ushort hb[16];
    #pragma unroll
    for (int e = 0; e < 16; ++e) hb[e] = f2bf(T[kq * 16 + e][nl]);
    if (z < 3) {
        const size_t o = (size_t)(z * 1024 + n0 + nl) * DMODEL + k0 + kq * 16;
        *reinterpret_cast<uint4*>(&wtc[o]) = *reinterpret_cast<uint4*>(&hb[0]);
        *reinterpret_cast<uint4*>(&wtc[o + 8]) = *reinterpret_cast<uint4*>(&hb[8]);
    } else {
        const size_t o = (size_t)(n0 + nl) * DMODEL + k0 + kq * 16;
        *reinterpret_cast<uint4*>(&woh[o]) = *reinterpret_cast<uint4*>(&hb[0]);
        *reinterpret_cast<uint4*>(&woh[o + 8]) = *reinterpret_cast<uint4*>(&hb[8]);
    }
}

// ---------------- fused QKV GEMM: 128x128 tile, BK=64, 256 thr, wave-tile 64x64 ----------------
__global__ __launch_bounds__(256, 3) void gemm_qkv(const ushort* __restrict__ xh,
                                                   const ushort* __restrict__ wtc,
                                                   ushort* __restrict__ Qb,
                                                   ushort* __restrict__ Kb,
                                                   ushort* __restrict__ Vtb) {
    __shared__ ushort SH[17408];   // Ah 16KB | Bh 16KB ; epilogue reuse VtL 128x136
    ushort* const Ah = SH;
    ushort* const Bh = SH + 8192;

    const int t = threadIdx.x, lane = t & 63, w = t >> 6;   // w 0..3
    const int l = lane & 15, g = lane >> 4;
    const int wm = w >> 1, wn = w & 1;                      // 2x2 wave grid
    const int bm = blockIdx.y * 128, bn = blockIdx.x * 128;

    f32x4 acc[4][4];
    #pragma unroll
    for (int mt = 0; mt < 4; ++mt)
        #pragma unroll
        for (int nt = 0; nt < 4; ++nt) acc[mt][nt] = (f32x4){0.f, 0.f, 0.f, 0.f};

    for (int kt = 0; kt < DMODEL; kt += 64) {
        __syncthreads();
        #pragma unroll
        for (int i = 0; i < 8; ++i) {
            const int sid = w * 8 + i;            // 0..31
            const int c = sid & 15;
            const ushort* src = (sid < 16) ? xh : wtc;
            const int rb = (sid < 16) ? bm : bn;
            ushort* dst = ((sid < 16) ? Ah : Bh) + c * 512;
            const int row = c * 8 + (lane >> 3);
            const int sw = ((lane & 7) ^ (row & 7)) << 3;
            GLD16(src + (size_t)(rb + row) * DMODEL + kt + sw, dst);
        }
        __syncthreads();

        bf16x8 af[4][2], bf[4][2];
        #pragma unroll
        for (int mt = 0; mt < 4; ++mt)
            #pragma unroll
            for (int s = 0; s < 2; ++s) {
                const int m = wm * 64 + mt * 16 + l;
                af[mt][s] = *reinterpret_cast<const bf16x8*>(&Ah[m * 64 + (((g + 4 * s) ^ (m & 7)) << 3)]);
            }
        #pragma unroll
        for (int nt = 0; nt < 4; ++nt)
            #pragma unroll
            for (int s = 0; s < 2; ++s) {
                const int n = wn * 64 + nt * 16 + l;
                bf[nt][s] = *reinterpret_cast<const bf16x8*>(&Bh[n * 64 + (((g + 4 * s) ^ (n & 7)) << 3)]);
            }
        __builtin_amdgcn_s_setprio(1);
        #pragma unroll
        for (int mt = 0; mt < 4; ++mt)
            #pragma unroll
            for (int nt = 0; nt < 4; ++nt)
                #pragma unroll
                for (int s = 0; s < 2; ++s)
                    acc[mt][nt] = __builtin_amdgcn_mfma_f32_16x16x32_bf16(af[mt][s], bf[nt][s], acc[mt][nt], 0, 0, 0);
        __builtin_amdgcn_s_setprio(0);
    }

    const int mode = bn >> 10;
    if (mode == 0) {
        #pragma unroll
        for (int mt = 0; mt < 4; ++mt)
            #pragma unroll
            for (int nt = 0; nt < 4; ++nt)
                #pragma unroll
                for (int r = 0; r < 4; ++r) {
                    const int row = bm + wm * 64 + mt * 16 + g * 4 + r;
                    const int col = bn + wn * 64 + nt * 16 + l;
                    Qb[(size_t)row * DMODEL + col] = f2bf(acc[mt][nt][r] * QSCALE);
                }
    } else if (mode == 1) {
        #pragma unroll
        for (int mt = 0; mt < 4; ++mt)
            #pragma unroll
            for (int nt = 0; nt < 4; ++nt)
                #pragma unroll
                for (int r = 0; r < 4; ++r) {
                    const int row = bm + wm * 64 + mt * 16 + g * 4 + r;
                    const int col = (bn - 1024) + wn * 64 + nt * 16 + l;
                    Kb[(size_t)row * DMODEL + col] = f2bf(acc[mt][nt][r]);
                }
    } else {
        __syncthreads();
        ushort* VtL = SH;   // [128 d][136 key]
        #pragma unroll
        for (int mt = 0; mt < 4; ++mt)
            #pragma unroll
            for (int nt = 0; nt < 4; ++nt)
                #pragma unroll
                for (int r = 0; r < 4; ++r) {
                    const int dl = wn * 64 + nt * 16 + l;
                    const int kl = wm * 64 + mt * 16 + g * 4 + r;
                    VtL[dl * 136 + kl] = f2bf(acc[mt][nt][r]);
                }
        __syncthreads();
        const int dl = t >> 1, kq = t & 1;        // 128 rows, 2 threads/row
        const int b = bm >> 11;
        const int row = b * 1024 + (bn - 2048) + dl;
        const int key0 = bm & 2047;
        const size_t o = (size_t)row * SEQ + key0 + kq * 64;
        #pragma unroll
        for (int j = 0; j < 8; ++j)               // 8 x uint4 = 64 keys/thread
            *reinterpret_cast<uint4*>(&Vtb[o + j * 8]) =
                *reinterpret_cast<uint4*>(&VtL[dl * 136 + kq * 64 + j * 8]);
    }
}

// ---------------- attention: swapped PV (P stays in registers), 5 blocks/CU ----------------
// Swapped QK leaves lane (g,l) holding P[q=l][key=16nt+4g+r]. PV is computed
// swapped too: O^T = mfma(A=V^T, B=P^T) with k-slot permutation
// kappa(32s+8g+e) = 16*(2s+(e>>2)) + 4g + (e&3), which makes the B-fragment the
// registers already held (pfB[s] = {p[2s][0..3], p[2s+1][0..3]}) and the A-side
// V^T read 4x b64 per dt with the same kappa. No P LDS roundtrip; Pl deleted
// (LDS 32KB -> 5 blocks/CU). accL via ones-A MFMA: accL[*] = l[q=l].
__global__ __launch_bounds__(256, 5) void attn(const ushort* __restrict__ Q,
                                               const ushort* __restrict__ K,
                                               const ushort* __restrict__ Vt,
                                               ushort* __restrict__ ATh) {
    __shared__ ushort Kl[2 * 4096];   // [buf][key 64][d 64] swizzled   16KB
    __shared__ ushort Vl[2 * 4096];   // [buf][d 64][key 64] swizzled   16KB -> 32KB

    const int t = threadIdx.x, lane = t & 63, w = t >> 6;
    const int l = lane & 15, g = lane >> 4;
    const int tile = 31 - blockIdx.y;             // heavy blocks dispatch first
    const int bh = blockIdx.x, b = bh >> 4, h = bh & 15;
    const size_t kbase = (size_t)b * SEQ * DMODEL + h * 64;
    const size_t vbase = (size_t)bh * 64 * SEQ;
    const int q0 = tile * 64 + w * 16;
    const int nch = tile + 1;

    // all-ones fragment (A-operand of the l row-sum MFMA)
    union { ushort u[8]; bf16x8 v; } onesu;
    #pragma unroll
    for (int e = 0; e < 8; ++e) onesu.u[e] = 0x3F80;   // bf16 1.0
    const bf16x8 ONES = onesu.v;

    // Q B-operand frags (col=q=lane&15, k=d=32s+8g+e)
    bf16x8 qf[2];
    {
        const size_t qo = (size_t)(b * SEQ + q0 + l) * DMODEL + h * 64 + 8 * g;
        qf[0] = *reinterpret_cast<const bf16x8*>(&Q[qo]);
        qf[1] = *reinterpret_cast<const bf16x8*>(&Q[qo + 32]);
    }

    f32x4 accO[4];   // accO[dt][r] = O[q=q0+l][d=dt*16+4g+r]
    #pragma unroll
    for (int dt = 0; dt < 4; ++dt) accO[dt] = (f32x4){0.f, 0.f, 0.f, 0.f};
    f32x4 accL = (f32x4){0.f, 0.f, 0.f, 0.f};   // accL[*] = l[q=q0+l]

    auto STAGE = [&](int buf, int kc) {
        const int k0 = kc * 64;
        if (w < 2) {
            #pragma unroll
            for (int i = 0; i < 4; ++i) {
                const int c = w * 4 + i;
                const int row = c * 8 + (lane >> 3);
                const int sw = ((lane & 7) ^ (row & 7)) << 3;
                GLD16(K + kbase + (size_t)(k0 + row) * DMODEL + sw,
                      Kl + buf * 4096 + c * 512);
            }
        } else {
            #pragma unroll
            for (int i = 0; i < 4; ++i) {
                const int c = (w - 2) * 4 + i;
                const int row = c * 8 + (lane >> 3);
                const int sw = ((lane & 7) ^ (row & 7)) << 3;
                GLD16(Vt + vbase + (size_t)row * SEQ + k0 + sw,
                      Vl + buf * 4096 + c * 512);
            }
        }
    };

    auto COMPUTE = [&](int buf, int kc) {
        const int k0 = kc * 64;
        const ushort* Kb_ = Kl + buf * 4096;
        const ushort* Vb_ = Vl + buf * 4096;
        const int xorsw0 = ((g + 0) ^ (l & 7)) << 3;
        const int xorsw1 = ((g + 4) ^ (l & 7)) << 3;

        bf16x8 kf[4][2];
        #pragma unroll
        for (int nt = 0; nt < 4; ++nt) {
            const int ro = (nt * 16 + l) * 64;
            kf[nt][0] = *reinterpret_cast<const bf16x8*>(&Kb_[ro + xorsw0]);
            kf[nt][1] = *reinterpret_cast<const bf16x8*>(&Kb_[ro + xorsw1]);
        }

        // swapped QK^T with C-init = -MFIX: sc[nt][r] = score[key=k0+16nt+4g+r][q=q0+l] - 16
        f32x4 sc[4];
        __builtin_amdgcn_s_setprio(1);
        #pragma unroll
        for (int nt = 0; nt < 4; ++nt) {
            f32x4 z = (f32x4){-MFIX, -MFIX, -MFIX, -MFIX};
            z = __builtin_amdgcn_mfma_f32_16x16x32_bf16(kf[nt][0], qf[0], z, 0, 0, 0);
            z = __builtin_amdgcn_mfma_f32_16x16x32_bf16(kf[nt][1], qf[1], z, 0, 0, 0);
            sc[nt] = z;
        }
        __builtin_amdgcn_s_setprio(0);

        // causal mask on the diagonal chunk
        if (kc == nch - 1) {
            const int qg = q0 + l;
            #pragma unroll
            for (int nt = 0; nt < 4; ++nt)
                #pragma unroll
                for (int r = 0; r < 4; ++r)
                    if (k0 + nt * 16 + g * 4 + r > qg) sc[nt][r] = -INFINITY;
        }

        // fixed-max softmax in registers: p = exp2(sc); pack B-fragments directly
        #pragma unroll
        for (int nt = 0; nt < 4; ++nt)
            #pragma unroll
            for (int r = 0; r < 4; ++r)
                sc[nt][r] = exp2f(sc[nt][r]);

        union { ushort4 h[2]; bf16x8 v; } pb0, pb1;
        pb0.h[0] = pack4bf(sc[0][0], sc[0][1], sc[0][2], sc[0][3]);
        pb0.h[1] = pack4bf(sc[1][0], sc[1][1], sc[1][2], sc[1][3]);
        pb1.h[0] = pack4bf(sc[2][0], sc[2][1], sc[2][2], sc[2][3]);
        pb1.h[1] = pack4bf(sc[3][0], sc[3][1], sc[3][2], sc[3][3]);

        // swapped PV: A = V^T rows d=dt*16+l, k-slots in kappa order (4x b64 per dt)
        const int lo = 4 * (g & 1);
        const int bb = g >> 1;
        const int x0 = ((0 + bb) ^ (l & 7)) << 3;
        const int x1 = ((2 + bb) ^ (l & 7)) << 3;
        const int x2 = ((4 + bb) ^ (l & 7)) << 3;
        const int x3 = ((6 + bb) ^ (l & 7)) << 3;
        __builtin_amdgcn_s_setprio(1);
        #pragma unroll
        for (int dt = 0; dt < 4; ++dt) {
            const int vrow = (dt * 16 + l) * 64;
            union { ushort4 h[2]; bf16x8 v; } va0, va1;
            va0.h[0] = *reinterpret_cast<const ushort4*>(&Vb_[vrow + x0 + lo]);
            va0.h[1] = *reinterpret_cast<const ushort4*>(&Vb_[vrow + x1 + lo]);
            va1.h[0] = *reinterpret_cast<const ushort4*>(&Vb_[vrow + x2 + lo]);
            va1.h[1] = *reinterpret_cast<const ushort4*>(&Vb_[vrow + x3 + lo]);
            accO[dt] = __builtin_amdgcn_mfma_f32_16x16x32_bf16(va0.v, pb0.v, accO[dt], 0, 0, 0);
            accO[dt] = __builtin_amdgcn_mfma_f32_16x16x32_bf16(va1.v, pb1.v, accO[dt], 0, 0, 0);
        }
        accL = __builtin_amdgcn_mfma_f32_16x16x32_bf16(ONES, pb0.v, accL, 0, 0, 0);
        accL = __builtin_amdgcn_mfma_f32_16x16x32_bf16(ONES, pb1.v, accL, 0, 0, 0);
        __builtin_amdgcn_s_setprio(0);
    };

    STAGE(0, 0);
    __syncthreads();

    int cur = 0;
    for (int kc = 0; kc < nch; ++kc) {
        if (kc + 1 < nch) STAGE(cur ^ 1, kc + 1);
        COMPUTE(cur, kc);
        __syncthreads();
        cur ^= 1;
    }

    // epilogue: lane owns row q=q0+l; accL[0] = l[q]; 4x ushort4 stores
    {
        const float inv = 1.f / accL[0];
        const size_t row = (size_t)(b * SEQ + q0 + l) * DMODEL + h * 64;
        #pragma unroll
        for (int dt = 0; dt < 4; ++dt) {
            const ushort4 o = pack4bf(accO[dt][0] * inv, accO[dt][1] * inv,
                                      accO[dt][2] * inv, accO[dt][3] * inv);
            *reinterpret_cast<ushort4*>(&ATh[row + dt * 16 + 4 * g]) = o;
        }
    }
}

// ---------------- out GEMM: single-pass Ah·Bh, 128x64 tile, BK=64, fp32 out ----------------
__global__ __launch_bounds__(512) void gemm_o(const ushort* __restrict__ Ahg,
                                              const ushort* __restrict__ Bhg,
                                              float* __restrict__ C) {
    __shared__ ushort SH[12288];   // Ah 16KB | Bh 8KB
    ushort* const Ah = SH;
    ushort* const Bh = SH + 8192;

    const int t = threadIdx.x, lane = t & 63, w = t >> 6;
    const int l = lane & 15, g = lane >> 4;
    const int wm = w >> 1, wn = w & 1;
    const int bm = blockIdx.y * 128, bn = blockIdx.x * 64;

    f32x4 acc[2][2];
    #pragma unroll
    for (int mt = 0; mt < 2; ++mt)
        #pragma unroll
        for (int nt = 0; nt < 2; ++nt) acc[mt][nt] = (f32x4){0.f, 0.f, 0.f, 0.f};

    for (int kt = 0; kt < DMODEL; kt += 64) {
        __syncthreads();
        #pragma unroll
        for (int i = 0; i < 3; ++i) {
            const int sid = w * 3 + i;            // 0..23
            const ushort* src; ushort* dst; int rb, c;
            if (sid < 16) { src = Ahg; dst = Ah; rb = bm; c = sid; }
            else          { src = Bhg; dst = Bh; rb = bn; c = sid - 16; }
            const int row = c * 8 + (lane >> 3);
            const int sw = ((lane & 7) ^ (row & 7)) << 3;
            GLD16(src + (size_t)(rb + row) * DMODEL + kt + sw, dst + c * 512);
        }
        __syncthreads();

        bf16x8 ah[2][2], bhf[2][2];
        #pragma unroll
        for (int mt = 0; mt < 2; ++mt)
            #pragma unroll
            for (int s = 0; s < 2; ++s) {
                const int m = wm * 32 + mt * 16 + l;
                ah[mt][s] = *reinterpret_cast<const bf16x8*>(&Ah[m * 64 + (((g + 4 * s) ^ (m & 7)) << 3)]);
            }
        #pragma unroll
        for (int nt = 0; nt < 2; ++nt)
            #pragma unroll
            for (int s = 0; s < 2; ++s) {
                const int n = wn * 32 + nt * 16 + l;
                bhf[nt][s] = *reinterpret_cast<const bf16x8*>(&Bh[n * 64 + (((g + 4 * s) ^ (n & 7)) << 3)]);
            }
        __builtin_amdgcn_s_setprio(1);
        #pragma unroll
        for (int mt = 0; mt < 2; ++mt)
            #pragma unroll
            for (int nt = 0; nt < 2; ++nt)
                #pragma unroll
                for (int s = 0; s < 2; ++s)
                    acc[mt][nt] = __builtin_amdgcn_mfma_f32_16x16x32_bf16(ah[mt][s], bhf[nt][s], acc[mt][nt], 0, 0, 0);
        __builtin_amdgcn_s_setprio(0);
    }

    #pragma unroll
    for (int mt = 0; mt < 2; ++mt)
        #pragma unroll
        for (int nt = 0; nt < 2; ++nt)
            #pragma unroll
            for (int r = 0; r < 4; ++r) {
                const int row = bm + wm * 32 + mt * 16 + g * 4 + r;
                const int col = bn + wn * 32 + nt * 16 + l;
                C[(size_t)row * DMODEL + col] = acc[mt][nt][r];
            }
}

// ---------------- launch ----------------
extern "C" void kernel_launch(void* const* d_in, const int* in_sizes, int n_in,
                              void* d_out, int out_size, void* d_ws, size_t ws_size,
                              hipStream_t stream) {
    const float* x  = (const float*)d_in[0];
    const float* Wq = (const float*)d_in[1];
    const float* Wk = (const float*)d_in[2];
    const float* Wv = (const float*)d_in[3];
    const float* Wo = (const float*)d_in[4];
    float* out = (float*)d_out;

    char* ws = (char*)d_ws;
    const size_t MB = 1024 * 1024;
    ushort* xh  = (ushort*)(ws);              // 8 MB (aliased as ATh after QKV gemm)
    ushort* ath = xh;
    ushort* wtc = (ushort*)(ws + 16 * MB);    // 6 MB  [3072][1024]
    ushort* woh = (ushort*)(ws + 22 * MB);    // 2 MB
    ushort* Qb  = (ushort*)(ws + 26 * MB);    // 8 MB
    ushort* Kb  = (ushort*)(ws + 34 * MB);    // 8 MB
    ushort* Vtb = (ushort*)(ws + 42 * MB);    // 8 MB

    prep<<<dim3(16, 16, 5), 256, 0, stream>>>(x, Wq, Wk, Wv, Wo, wtc, woh, xh);

    gemm_qkv<<<dim3(24, 32), 256, 0, stream>>>(xh, wtc, Qb, Kb, Vtb);

    attn<<<dim3(32, 32), 256, 0, stream>>>(Qb, Kb, Vtb, ath);

    gemm_o<<<dim3(16, 32), 512, 0, stream>>>(ath, woh, out);
}

// Round 22
// 102.730 us; speedup vs baseline: 1.0415x; 1.0415x over previous
//
#include <hip/hip_runtime.h>
#include <math.h>

#define BATCH 2
#define SEQ   2048
#define DMODEL 1024
#define NHEAD 16
#define HEADD 64
#define MROWS 4096

typedef __attribute__((ext_vector_type(8))) __bf16 bf16x8;
typedef __attribute__((ext_vector_type(4))) float f32x4;

__device__ __forceinline__ ushort f2bf(float f) {
    uint u = __float_as_uint(f);
    u += 0x7fffu + ((u >> 16) & 1u);
    return (ushort)(u >> 16);
}
__device__ __forceinline__ float bf2f(ushort h) {
    return __uint_as_float(((uint)h) << 16);
}
__device__ __forceinline__ ushort4 pack4bf(float a, float b, float c, float d) {
    union { __bf16 h[4]; ushort4 u; } p;
    p.h[0] = (__bf16)a; p.h[1] = (__bf16)b; p.h[2] = (__bf16)c; p.h[3] = (__bf16)d;
    return p.u;
}

#define GLD16(gsrc, ldst)                                                         \
    __builtin_amdgcn_global_load_lds(                                             \
        (const __attribute__((address_space(1))) unsigned int*)(gsrc),            \
        (__attribute__((address_space(3))) unsigned int*)(ldst), 16, 0, 0)

// Q pre-scale: (1/sqrt(64)) * log2(e)  -> softmax in exp2 domain
#define QSCALE 0.1803368801111204f
#define MFIX   16.0f   // fixed softmax "max", folded into QK MFMA C-init

// ---------------- merged prep: z<3 -> W^T->wtc; z==3 -> Wo^T->woh; z==4 -> x split ----------------
__global__ __launch_bounds__(256) void prep(const float* __restrict__ x,
                                            const float* __restrict__ Wq,
                                            const float* __restrict__ Wk,
                                            const float* __restrict__ Wv,
                                            const float* __restrict__ Wo,
                                            ushort* __restrict__ wtc,
                                            ushort* __restrict__ woh,
                                            ushort* __restrict__ xh) {
    const int z = blockIdx.z;
    const int t = threadIdx.x;
    if (z == 4) {
        const int n4 = MROWS * DMODEL / 4;
        int i = (blockIdx.y * 16 + blockIdx.x) * 256 + t;
        const int stride = 256 * 256;
        for (; i < n4; i += stride) {
            const float4 v = reinterpret_cast<const float4*>(x)[i];
            ushort4 h;
            h.x = f2bf(v.x); h.y = f2bf(v.y); h.z = f2bf(v.z); h.w = f2bf(v.w);
            reinterpret_cast<ushort4*>(xh)[i] = h;
        }
        return;
    }
    const float* W = (z == 0) ? Wq : (z == 1) ? Wk : (z == 2) ? Wv : Wo;
    __shared__ float T[64][68];
    const int k0 = blockIdx.y * 64, n0 = blockIdx.x * 64;
    {
        const int r = t >> 2, c0 = (t & 3) * 16;
        #pragma unroll
        for (int j = 0; j < 4; ++j)
            *reinterpret_cast<float4*>(&T[r][c0 + j * 4]) =
                *reinterpret_cast<const float4*>(&W[(size_t)(k0 + r) * DMODEL + n0 + c0 + j * 4]);
    }
    __syncthreads();
    const int nl = t >> 2, kq = t & 3;
    ushort hb[16];
    #pragma unroll
    for (int e = 0; e < 16; ++e) hb[e] = f2bf(T[kq * 16 + e][nl]);
    if (z < 3) {
        const size_t o = (size_t)(z * 1024 + n0 + nl) * DMODEL + k0 + kq * 16;
        *reinterpret_cast<uint4*>(&wtc[o]) = *reinterpret_cast<uint4*>(&hb[0]);
        *reinterpret_cast<uint4*>(&wtc[o + 8]) = *reinterpret_cast<uint4*>(&hb[8]);
    } else {
        const size_t o = (size_t)(n0 + nl) * DMODEL + k0 + kq * 16;
        *reinterpret_cast<uint4*>(&woh[o]) = *reinterpret_cast<uint4*>(&hb[0]);
        *reinterpret_cast<uint4*>(&woh[o + 8]) = *reinterpret_cast<uint4*>(&hb[8]);
    }
}

// ---------------- fused QKV GEMM: 128x128 tile, BK=64, 256 thr, wave-tile 64x64 ----------------
__global__ __launch_bounds__(256, 3) void gemm_qkv(const ushort* __restrict__ xh,
                                                   const ushort* __restrict__ wtc,
                                                   ushort* __restrict__ Qb,
                                                   ushort* __restrict__ Kb,
                                                   ushort* __restrict__ Vtb) {
    __shared__ ushort SH[17408];   // Ah 16KB | Bh 16KB ; epilogue reuse VtL 128x136
    ushort* const Ah = SH;
    ushort* const Bh = SH + 8192;

    const int t = threadIdx.x, lane = t & 63, w = t >> 6;   // w 0..3
    const int l = lane & 15, g = lane >> 4;
    const int wm = w >> 1, wn = w & 1;                      // 2x2 wave grid
    const int bm = blockIdx.y * 128, bn = blockIdx.x * 128;

    f32x4 acc[4][4];
    #pragma unroll
    for (int mt = 0; mt < 4; ++mt)
        #pragma unroll
        for (int nt = 0; nt < 4; ++nt) acc[mt][nt] = (f32x4){0.f, 0.f, 0.f, 0.f};

    for (int kt = 0; kt < DMODEL; kt += 64) {
        __syncthreads();
        #pragma unroll
        for (int i = 0; i < 8; ++i) {
            const int sid = w * 8 + i;            // 0..31
            const int c = sid & 15;
            const ushort* src = (sid < 16) ? xh : wtc;
            const int rb = (sid < 16) ? bm : bn;
            ushort* dst = ((sid < 16) ? Ah : Bh) + c * 512;
            const int row = c * 8 + (lane >> 3);
            const int sw = ((lane & 7) ^ (row & 7)) << 3;
            GLD16(src + (size_t)(rb + row) * DMODEL + kt + sw, dst);
        }
        __syncthreads();

        bf16x8 af[4][2], bf[4][2];
        #pragma unroll
        for (int mt = 0; mt < 4; ++mt)
            #pragma unroll
            for (int s = 0; s < 2; ++s) {
                const int m = wm * 64 + mt * 16 + l;
                af[mt][s] = *reinterpret_cast<const bf16x8*>(&Ah[m * 64 + (((g + 4 * s) ^ (m & 7)) << 3)]);
            }
        #pragma unroll
        for (int nt = 0; nt < 4; ++nt)
            #pragma unroll
            for (int s = 0; s < 2; ++s) {
                const int n = wn * 64 + nt * 16 + l;
                bf[nt][s] = *reinterpret_cast<const bf16x8*>(&Bh[n * 64 + (((g + 4 * s) ^ (n & 7)) << 3)]);
            }
        __builtin_amdgcn_s_setprio(1);
        #pragma unroll
        for (int mt = 0; mt < 4; ++mt)
            #pragma unroll
            for (int nt = 0; nt < 4; ++nt)
                #pragma unroll
                for (int s = 0; s < 2; ++s)
                    acc[mt][nt] = __builtin_amdgcn_mfma_f32_16x16x32_bf16(af[mt][s], bf[nt][s], acc[mt][nt], 0, 0, 0);
        __builtin_amdgcn_s_setprio(0);
    }

    const int mode = bn >> 10;
    if (mode == 0) {
        #pragma unroll
        for (int mt = 0; mt < 4; ++mt)
            #pragma unroll
            for (int nt = 0; nt < 4; ++nt)
                #pragma unroll
                for (int r = 0; r < 4; ++r) {
                    const int row = bm + wm * 64 + mt * 16 + g * 4 + r;
                    const int col = bn + wn * 64 + nt * 16 + l;
                    Qb[(size_t)row * DMODEL + col] = f2bf(acc[mt][nt][r] * QSCALE);
                }
    } else if (mode == 1) {
        #pragma unroll
        for (int mt = 0; mt < 4; ++mt)
            #pragma unroll
            for (int nt = 0; nt < 4; ++nt)
                #pragma unroll
                for (int r = 0; r < 4; ++r) {
                    const int row = bm + wm * 64 + mt * 16 + g * 4 + r;
                    const int col = (bn - 1024) + wn * 64 + nt * 16 + l;
                    Kb[(size_t)row * DMODEL + col] = f2bf(acc[mt][nt][r]);
                }
    } else {
        __syncthreads();
        ushort* VtL = SH;   // [128 d][136 key]
        #pragma unroll
        for (int mt = 0; mt < 4; ++mt)
            #pragma unroll
            for (int nt = 0; nt < 4; ++nt)
                #pragma unroll
                for (int r = 0; r < 4; ++r) {
                    const int dl = wn * 64 + nt * 16 + l;
                    const int kl = wm * 64 + mt * 16 + g * 4 + r;
                    VtL[dl * 136 + kl] = f2bf(acc[mt][nt][r]);
                }
        __syncthreads();
        const int dl = t >> 1, kq = t & 1;        // 128 rows, 2 threads/row
        const int b = bm >> 11;
        const int row = b * 1024 + (bn - 2048) + dl;
        const int key0 = bm & 2047;
        const size_t o = (size_t)row * SEQ + key0 + kq * 64;
        #pragma unroll
        for (int j = 0; j < 8; ++j)               // 8 x uint4 = 64 keys/thread
            *reinterpret_cast<uint4*>(&Vtb[o + j * 8]) =
                *reinterpret_cast<uint4*>(&VtL[dl * 136 + kq * 64 + j * 8]);
    }
}

// ---------------- attention: fixed-max softmax, l via ones-MFMA, 4 blocks/CU ----------------
// (r20 configuration — best measured: 102.8 us total)
__global__ __launch_bounds__(256, 4) void attn(const ushort* __restrict__ Q,
                                               const ushort* __restrict__ K,
                                               const ushort* __restrict__ Vt,
                                               ushort* __restrict__ ATh) {
    __shared__ ushort Kl[2 * 4096];   // [buf][key 64][d 64] swizzled   16KB
    __shared__ ushort Vl[2 * 4096];   // [buf][d 64][key 64] swizzled   16KB
    __shared__ ushort Pl[4096];       // [64 q][64 key] XOR-swizzled     8KB -> 40KB

    const int t = threadIdx.x, lane = t & 63, w = t >> 6;
    const int l = lane & 15, g = lane >> 4;
    const int tile = 31 - blockIdx.y;             // heavy blocks dispatch first
    const int bh = blockIdx.x, b = bh >> 4, h = bh & 15;
    const size_t kbase = (size_t)b * SEQ * DMODEL + h * 64;
    const size_t vbase = (size_t)bh * 64 * SEQ;
    const int q0 = tile * 64 + w * 16;
    const int nch = tile + 1;

    // all-ones B fragment for the row-sum MFMA
    union { ushort u[8]; bf16x8 v; } onesu;
    #pragma unroll
    for (int e = 0; e < 8; ++e) onesu.u[e] = 0x3F80;   // bf16 1.0
    const bf16x8 ONES = onesu.v;

    // Q B-operand frags (col=q=lane&15, k=d=32s+8g+e)
    bf16x8 qf[2];
    {
        const size_t qo = (size_t)(b * SEQ + q0 + l) * DMODEL + h * 64 + 8 * g;
        qf[0] = *reinterpret_cast<const bf16x8*>(&Q[qo]);
        qf[1] = *reinterpret_cast<const bf16x8*>(&Q[qo + 32]);
    }

    f32x4 accO[4];
    #pragma unroll
    for (int dt = 0; dt < 4; ++dt) accO[dt] = (f32x4){0.f, 0.f, 0.f, 0.f};
    f32x4 accL = (f32x4){0.f, 0.f, 0.f, 0.f};   // accL[r] = l[q = 4g+r]

    auto STAGE = [&](int buf, int kc) {
        const int k0 = kc * 64;
        if (w < 2) {
            #pragma unroll
            for (int i = 0; i < 4; ++i) {
                const int c = w * 4 + i;
                const int row = c * 8 + (lane >> 3);
                const int sw = ((lane & 7) ^ (row & 7)) << 3;
                GLD16(K + kbase + (size_t)(k0 + row) * DMODEL + sw,
                      Kl + buf * 4096 + c * 512);
            }
        } else {
            #pragma unroll
            for (int i = 0; i < 4; ++i) {
                const int c = (w - 2) * 4 + i;
                const int row = c * 8 + (lane >> 3);
                const int sw = ((lane & 7) ^ (row & 7)) << 3;
                GLD16(Vt + vbase + (size_t)row * SEQ + k0 + sw,
                      Vl + buf * 4096 + c * 512);
            }
        }
    };

    auto COMPUTE = [&](int buf, int kc) {
        const int k0 = kc * 64;
        const ushort* Kb_ = Kl + buf * 4096;
        const ushort* Vb_ = Vl + buf * 4096;
        const int xorsw0 = ((g + 0) ^ (l & 7)) << 3;
        const int xorsw1 = ((g + 4) ^ (l & 7)) << 3;

        bf16x8 kf[4][2];
        #pragma unroll
        for (int nt = 0; nt < 4; ++nt) {
            const int ro = (nt * 16 + l) * 64;
            kf[nt][0] = *reinterpret_cast<const bf16x8*>(&Kb_[ro + xorsw0]);
            kf[nt][1] = *reinterpret_cast<const bf16x8*>(&Kb_[ro + xorsw1]);
        }

        // swapped QK^T with C-init = -MFIX: sc = QK - 16 directly
        f32x4 sc[4];
        __builtin_amdgcn_s_setprio(1);
        #pragma unroll
        for (int nt = 0; nt < 4; ++nt) {
            f32x4 z = (f32x4){-MFIX, -MFIX, -MFIX, -MFIX};
            z = __builtin_amdgcn_mfma_f32_16x16x32_bf16(kf[nt][0], qf[0], z, 0, 0, 0);
            z = __builtin_amdgcn_mfma_f32_16x16x32_bf16(kf[nt][1], qf[1], z, 0, 0, 0);
            sc[nt] = z;
        }
        __builtin_amdgcn_s_setprio(0);

        // causal mask on the diagonal chunk
        if (kc == nch - 1) {
            const int qg = q0 + l;
            #pragma unroll
            for (int nt = 0; nt < 4; ++nt)
                #pragma unroll
                for (int r = 0; r < 4; ++r)
                    if (k0 + nt * 16 + g * 4 + r > qg) sc[nt][r] = -INFINITY;
        }

        // fixed-max softmax: p = exp2(sc); P -> LDS (l comes from ones-MFMA later)
        {
            #pragma unroll
            for (int nt = 0; nt < 4; ++nt)
                #pragma unroll
                for (int r = 0; r < 4; ++r)
                    sc[nt][r] = exp2f(sc[nt][r]);

            const int prow = w * 16 + l;
            #pragma unroll
            for (int nt = 0; nt < 4; ++nt)
                *reinterpret_cast<ushort4*>(
                    &Pl[prow * 64 + ((nt * 16 + 4 * g) ^ ((l & 7) << 3))]) =
                    pack4bf(sc[nt][0], sc[nt][1], sc[nt][2], sc[nt][3]);
        }

        // V frags from LDS (row=d=16dt+l) + PV + ones-MFMA row-sum
        bf16x8 vf[4][2];
        #pragma unroll
        for (int dt = 0; dt < 4; ++dt) {
            const int ro = (dt * 16 + l) * 64;
            vf[dt][0] = *reinterpret_cast<const bf16x8*>(&Vb_[ro + xorsw0]);
            vf[dt][1] = *reinterpret_cast<const bf16x8*>(&Vb_[ro + xorsw1]);
        }
        bf16x8 pf[2];
        const int prow = w * 16 + l;
        pf[0] = *reinterpret_cast<const bf16x8*>(&Pl[prow * 64 + ((8 * g) ^ ((l & 7) << 3))]);
        pf[1] = *reinterpret_cast<const bf16x8*>(&Pl[prow * 64 + ((32 + 8 * g) ^ ((l & 7) << 3))]);
        __builtin_amdgcn_s_setprio(1);
        #pragma unroll
        for (int dt = 0; dt < 4; ++dt) {
            accO[dt] = __builtin_amdgcn_mfma_f32_16x16x32_bf16(pf[0], vf[dt][0], accO[dt], 0, 0, 0);
            accO[dt] = __builtin_amdgcn_mfma_f32_16x16x32_bf16(pf[1], vf[dt][1], accO[dt], 0, 0, 0);
        }
        accL = __builtin_amdgcn_mfma_f32_16x16x32_bf16(pf[0], ONES, accL, 0, 0, 0);
        accL = __builtin_amdgcn_mfma_f32_16x16x32_bf16(pf[1], ONES, accL, 0, 0, 0);
        __builtin_amdgcn_s_setprio(0);
    };

    STAGE(0, 0);
    __syncthreads();

    int cur = 0;
    for (int kc = 0; kc < nch; ++kc) {
        if (kc + 1 < nch) STAGE(cur ^ 1, kc + 1);
        COMPUTE(cur, kc);
        __syncthreads();
        cur ^= 1;
    }

    // epilogue: accL[r] already holds l[q=4g+r]; normalize, emit attended bf16
    #pragma unroll
    for (int r = 0; r < 4; ++r) {
        const float inv = 1.f / accL[r];
        const size_t row = (size_t)(b * SEQ + q0 + g * 4 + r) * DMODEL + h * 64;
        #pragma unroll
        for (int dt = 0; dt < 4; ++dt)
            ATh[row + dt * 16 + l] = f2bf(accO[dt][r] * inv);
    }
}

// ---------------- out GEMM: single-pass Ah·Bh, 128x64 tile, BK=64, fp32 out ----------------
__global__ __launch_bounds__(512) void gemm_o(const ushort* __restrict__ Ahg,
                                              const ushort* __restrict__ Bhg,
                                              float* __restrict__ C) {
    __shared__ ushort SH[12288];   // Ah 16KB | Bh 8KB
    ushort* const Ah = SH;
    ushort* const Bh = SH + 8192;

    const int t = threadIdx.x, lane = t & 63, w = t >> 6;
    const int l = lane & 15, g = lane >> 4;
    const int wm = w >> 1, wn = w & 1;
    const int bm = blockIdx.y * 128, bn = blockIdx.x * 64;

    f32x4 acc[2][2];
    #pragma unroll
    for (int mt = 0; mt < 2; ++mt)
        #pragma unroll
        for (int nt = 0; nt < 2; ++nt) acc[mt][nt] = (f32x4){0.f, 0.f, 0.f, 0.f};

    for (int kt = 0; kt < DMODEL; kt += 64) {
        __syncthreads();
        #pragma unroll
        for (int i = 0; i < 3; ++i) {
            const int sid = w * 3 + i;            // 0..23
            const ushort* src; ushort* dst; int rb, c;
            if (sid < 16) { src = Ahg; dst = Ah; rb = bm; c = sid; }
            else          { src = Bhg; dst = Bh; rb = bn; c = sid - 16; }
            const int row = c * 8 + (lane >> 3);
            const int sw = ((lane & 7) ^ (row & 7)) << 3;
            GLD16(src + (size_t)(rb + row) * DMODEL + kt + sw, dst + c * 512);
        }
        __syncthreads();

        bf16x8 ah[2][2], bhf[2][2];
        #pragma unroll
        for (int mt = 0; mt < 2; ++mt)
            #pragma unroll
            for (int s = 0; s < 2; ++s) {
                const int m = wm * 32 + mt * 16 + l;
                ah[mt][s] = *reinterpret_cast<const bf16x8*>(&Ah[m * 64 + (((g + 4 * s) ^ (m & 7)) << 3)]);
            }
        #pragma unroll
        for (int nt = 0; nt < 2; ++nt)
            #pragma unroll
            for (int s = 0; s < 2; ++s) {
                const int n = wn * 32 + nt * 16 + l;
                bhf[nt][s] = *reinterpret_cast<const bf16x8*>(&Bh[n * 64 + (((g + 4 * s) ^ (n & 7)) << 3)]);
            }
        __builtin_amdgcn_s_setprio(1);
        #pragma unroll
        for (int mt = 0; mt < 2; ++mt)
            #pragma unroll
            for (int nt = 0; nt < 2; ++nt)
                #pragma unroll
                for (int s = 0; s < 2; ++s)
                    acc[mt][nt] = __builtin_amdgcn_mfma_f32_16x16x32_bf16(ah[mt][s], bhf[nt][s], acc[mt][nt], 0, 0, 0);
        __builtin_amdgcn_s_setprio(0);
    }

    #pragma unroll
    for (int mt = 0; mt < 2; ++mt)
        #pragma unroll
        for (int nt = 0; nt < 2; ++nt)
            #pragma unroll
            for (int r = 0; r < 4; ++r) {
                const int row = bm + wm * 32 + mt * 16 + g * 4 + r;
                const int col = bn + wn * 32 + nt * 16 + l;
                C[(size_t)row * DMODEL + col] = acc[mt][nt][r];
            }
}

// ---------------- launch ----------------
extern "C" void kernel_launch(void* const* d_in, const int* in_sizes, int n_in,
                              void* d_out, int out_size, void* d_ws, size_t ws_size,
                              hipStream_t stream) {
    const float* x  = (const float*)d_in[0];
    const float* Wq = (const float*)d_in[1];
    const float* Wk = (const float*)d_in[2];
    const float* Wv = (const float*)d_in[3];
    const float* Wo = (const float*)d_in[4];
    float* out = (float*)d_out;

    char* ws = (char*)d_ws;
    const size_t MB = 1024 * 1024;
    ushort* xh  = (ushort*)(ws);              // 8 MB (aliased as ATh after QKV gemm)
    ushort* ath = xh;
    ushort* wtc = (ushort*)(ws + 16 * MB);    // 6 MB  [3072][1024]
    ushort* woh = (ushort*)(ws + 22 * MB);    // 2 MB
    ushort* Qb  = (ushort*)(ws + 26 * MB);    // 8 MB
    ushort* Kb  = (ushort*)(ws + 34 * MB);    // 8 MB
    ushort* Vtb = (ushort*)(ws + 42 * MB);    // 8 MB

    prep<<<dim3(16, 16, 5), 256, 0, stream>>>(x, Wq, Wk, Wv, Wo, wtc, woh, xh);

    gemm_qkv<<<dim3(24, 32), 256, 0, stream>>>(xh, wtc, Qb, Kb, Vtb);

    attn<<<dim3(32, 32), 256, 0, stream>>>(Qb, Kb, Vtb, ath);

    gemm_o<<<dim3(16, 32), 512, 0, stream>>>(ath, woh, out);
}